// Round 2
// baseline (609.672 us; speedup 1.0000x reference)
//
#include <hip/hip_runtime.h>

// Problem constants
#define N_TOK 8192
#define DIM   4096
#define NEXP  8
#define RANK  128
#define EK    (NEXP * RANK)   // 1024 = flattened (expert, rank) K dim for GEMM2
#define SCAL  0.25f           // LORA_ALPHA / R = 32/128

typedef unsigned short u16;
typedef __bf16 bf16x8 __attribute__((ext_vector_type(8)));
typedef float  f32x4  __attribute__((ext_vector_type(4)));

typedef const __attribute__((address_space(1))) void* as1_cvp;
typedef __attribute__((address_space(3))) void*       as3_vp;

__device__ __forceinline__ void async16(void* lds, const void* g) {
  // 16B-per-lane direct global->LDS (global_load_lds_dwordx4). LDS dest must be
  // wave-uniform base + lane*16 — all call sites arrange lds = base + tid*16B.
  __builtin_amdgcn_global_load_lds((as1_cvp)g, (as3_vp)lds, 16, 0, 0);
}

__device__ __forceinline__ u16 f2bf(float f) {  // RNE float->bf16 bits
  unsigned int u = __builtin_bit_cast(unsigned int, f);
  u += 0x7fffu + ((u >> 16) & 1u);
  return (u16)(u >> 16);
}

__device__ __forceinline__ f32x4 mfma16(bf16x8 a, bf16x8 b, f32x4 c) {
  return __builtin_amdgcn_mfma_f32_16x16x32_bf16(a, b, c, 0, 0, 0);
}

// ---------------------------------------------------------------- converts
__global__ __launch_bounds__(256) void cvtA_kernel(const float* __restrict__ A,
                                                   u16* __restrict__ Ab) {
  size_t i = (size_t)blockIdx.x * 256 + threadIdx.x;  // float4 index, same layout
  float4 v = ((const float4*)A)[i];
  ushort4 o;
  o.x = f2bf(v.x); o.y = f2bf(v.y); o.z = f2bf(v.z); o.w = f2bf(v.w);
  ((ushort4*)Ab)[i] = o;
}

// B[e][o][r] fp32 -> Bt[o][e*128+r] bf16 (BT layout for GEMM2, k-contiguous rows)
__global__ __launch_bounds__(256) void cvtB_kernel(const float* __restrict__ B,
                                                   u16* __restrict__ Bt) {
  size_t i = (size_t)blockIdx.x * 256 + threadIdx.x;  // enumerates (e, o, r/4)
  int r4 = (int)(i & 31);
  int o_ = (int)((i >> 5) & 4095);
  int e  = (int)(i >> 17);
  float4 v = ((const float4*)B)[i];
  ushort4 u;
  u.x = f2bf(v.x); u.y = f2bf(v.y); u.z = f2bf(v.z); u.w = f2bf(v.w);
  ((ushort4*)Bt)[(size_t)o_ * 256 + e * 32 + r4] = u;
}

// ---------------------------------------------------------------- router
// fp32 router (bf16 would flip near-tie expert picks), fused x->bf16 convert,
// per-expert entry-list build.
// R1 fix: old version did a 6-step x 8-expert shuffle butterfly PER TOKEN per
// wave (48 DS ops / 4 loaded floats) -> LDS-pipe bound at 151 us (VALUBusy 8%,
// HBM 11%, 260K bank conflicts). New shape: one wave owns 2 tokens, lanes
// accumulate 8 expert partials across all D=4096 (16 coalesced float4 iters),
// ONE butterfly at the end. DS ops per element: 12 -> 0.023.
__device__ __forceinline__ void router_finalize(
    int n, const float* l_in, const float* __restrict__ br,
    float* __restrict__ gw, int* __restrict__ lists, int* __restrict__ cnt) {
  float l[NEXP];
#pragma unroll
  for (int e = 0; e < NEXP; ++e) l[e] = l_in[e] + br[e];
  int i0 = 0;
#pragma unroll
  for (int e = 1; e < NEXP; ++e) if (l[e] > l[i0]) i0 = e;
  int i1 = (i0 == 0) ? 1 : 0;
#pragma unroll
  for (int e = 0; e < NEXP; ++e) if (e != i0 && l[e] > l[i1]) i1 = e;
  // renormalized top-2 gate: w0 = exp(l0)/(exp(l0)+exp(l1)); l1<=l0 so no ovf
  float w0 = 1.f / (1.f + expf(l[i1] - l[i0]));
  gw[n * 2 + 0] = w0 * SCAL;
  gw[n * 2 + 1] = (1.f - w0) * SCAL;
  int p;
  p = atomicAdd(&cnt[i0], 1); lists[i0 * N_TOK + p] = n * 2;
  p = atomicAdd(&cnt[i1], 1); lists[i1 * N_TOK + p] = n * 2 + 1;
}

__global__ __launch_bounds__(256) void router_kernel(
    const float* __restrict__ x, const float* __restrict__ Wr,
    const float* __restrict__ br, u16* __restrict__ xb,
    float* __restrict__ gw, int* __restrict__ lists, int* __restrict__ cnt) {
  const int tid = threadIdx.x;
  const int wv = tid >> 6, lane = tid & 63;
  const int n0 = (blockIdx.x * 4 + wv) * 2;  // this wave's 2 tokens
  const float4* x4 = (const float4*)x;
  const float4* w4 = (const float4*)Wr;

  const float4* xr0 = x4 + (size_t)n0 * 1024;
  const float4* xr1 = x4 + (size_t)(n0 + 1) * 1024;
  ushort4* xo0 = (ushort4*)(xb + (size_t)n0 * DIM);
  ushort4* xo1 = (ushort4*)(xb + (size_t)(n0 + 1) * DIM);

  float s0[NEXP] = {}, s1[NEXP] = {};
#pragma unroll 4
  for (int it = 0; it < 16; ++it) {
    const int col = it * 64 + lane;  // float4 column index; lanes coalesced
    float4 xv0 = xr0[col];
    float4 xv1 = xr1[col];
    ushort4 o0, o1;
    o0.x = f2bf(xv0.x); o0.y = f2bf(xv0.y); o0.z = f2bf(xv0.z); o0.w = f2bf(xv0.w);
    o1.x = f2bf(xv1.x); o1.y = f2bf(xv1.y); o1.z = f2bf(xv1.z); o1.w = f2bf(xv1.w);
    xo0[col] = o0;
    xo1[col] = o1;
#pragma unroll
    for (int e = 0; e < NEXP; ++e) {
      float4 wv4 = w4[(size_t)e * 1024 + col];  // L2-resident (128 KB total)
      s0[e] += xv0.x * wv4.x + xv0.y * wv4.y + xv0.z * wv4.z + xv0.w * wv4.w;
      s1[e] += xv1.x * wv4.x + xv1.y * wv4.y + xv1.z * wv4.z + xv1.w * wv4.w;
    }
  }
  // one butterfly per wave (96 DS ops for 8192 loaded floats)
#pragma unroll
  for (int m = 1; m < 64; m <<= 1)
#pragma unroll
    for (int e = 0; e < NEXP; ++e) {
      s0[e] += __shfl_xor(s0[e], m, 64);
      s1[e] += __shfl_xor(s1[e], m, 64);
    }
  if (lane == 0)      router_finalize(n0,     s0, br, gw, lists, cnt);
  else if (lane == 1) router_finalize(n0 + 1, s1, br, gw, lists, cnt);
}

// ---------------------------------------------------------------- GEMM1
// Per expert: h[entry, r] = xb[token] . Ab[e][r], scaled by gate*SCAL -> G bf16.
// Tile: 64 entries x 128 (full R) x BK=64, 256 threads (4 waves, each 32x64).
__global__ __launch_bounds__(256) void gemm1_kernel(
    const u16* __restrict__ xb, const u16* __restrict__ Ab,
    const int* __restrict__ lists, const int* __restrict__ cnt,
    const float* __restrict__ gw, u16* __restrict__ G) {
  const int e = blockIdx.y;
  const int mt = blockIdx.x;
  const int c = cnt[e];
  if (mt * 64 >= c) return;

  __shared__ alignas(16) u16 As[64 * 64];
  __shared__ alignas(16) u16 Bs[128 * 64];
  __shared__ int   tokS[64];
  __shared__ float wS[64];

  const int tid = threadIdx.x;
  if (tid < 64) {
    int idx = mt * 64 + tid;
    int ci = idx < c ? idx : (c - 1);
    int entry = lists[e * N_TOK + ci];
    tokS[tid] = entry >> 1;
    wS[tid] = (idx < c) ? gw[entry] : 0.0f;
  }
  __syncthreads();

  const int lr = tid >> 3;  // 0..31 staging row
  const int cg = tid & 7;   // 16B column group
  const u16* ga0 = xb + (size_t)tokS[lr] * DIM + cg * 8;
  const u16* ga1 = xb + (size_t)tokS[lr + 32] * DIM + cg * 8;
  const u16* gb  = Ab + (size_t)e * (RANK * DIM) + (size_t)lr * DIM + cg * 8;

  const int lane = tid & 63, wvi = tid >> 6;
  const int wm = wvi >> 1, wn = wvi & 1;
  const int m16 = lane & 15, quad = lane >> 4;

  f32x4 acc[2][4] = {};

  for (int k0 = 0; k0 < DIM; k0 += 64) {
    async16(&As[tid * 8], ga0 + k0);
    async16(&As[tid * 8 + 2048], ga1 + k0);
#pragma unroll
    for (int r = 0; r < 4; ++r)
      async16(&Bs[tid * 8 + r * 2048], gb + (size_t)r * 32 * DIM + k0);
    __syncthreads();
#pragma unroll
    for (int ks = 0; ks < 2; ++ks) {
      const int ko = ks * 32 + quad * 8;
      bf16x8 af[2], bfr[4];
#pragma unroll
      for (int i = 0; i < 2; ++i)
        af[i] = *(const bf16x8*)&As[(wm * 32 + i * 16 + m16) * 64 + ko];
#pragma unroll
      for (int j = 0; j < 4; ++j)
        bfr[j] = *(const bf16x8*)&Bs[(wn * 64 + j * 16 + m16) * 64 + ko];
#pragma unroll
      for (int i = 0; i < 2; ++i)
#pragma unroll
        for (int j = 0; j < 4; ++j) acc[i][j] = mfma16(af[i], bfr[j], acc[i][j]);
    }
    __syncthreads();
  }

#pragma unroll
  for (int i = 0; i < 2; ++i)
#pragma unroll
    for (int rr = 0; rr < 4; ++rr) {
      int row = wm * 32 + i * 16 + quad * 4 + rr;  // C/D: row=quad*4+reg
      if (mt * 64 + row < c) {
        int tk = tokS[row];
        float wgt = wS[row];
        u16* gp = G + (size_t)tk * EK + e * RANK + wn * 64 + m16;  // col=lane&15
#pragma unroll
        for (int j = 0; j < 4; ++j) gp[j * 16] = f2bf(acc[i][j][rr] * wgt);
      }
    }
}

// ---------------------------------------------------------------- GEMM2
// Dense: out[8192,4096] = G[8192,1024] @ Bt[4096,1024]^T. m97-style 128x128x64.
__global__ __launch_bounds__(256) void gemm2_kernel(
    const u16* __restrict__ G, const u16* __restrict__ Bt,
    float* __restrict__ out) {
  const int bx = blockIdx.x;  // n tile 0..31
  const int by = blockIdx.y;  // m tile 0..63
  __shared__ alignas(16) u16 As[128 * 64];
  __shared__ alignas(16) u16 Bs[128 * 64];

  const int tid = threadIdx.x;
  const int lr = tid >> 3, cg = tid & 7;
  const u16* ga = G  + (size_t)(by * 128 + lr) * EK + cg * 8;
  const u16* gb = Bt + (size_t)(bx * 128 + lr) * EK + cg * 8;

  const int lane = tid & 63, wvi = tid >> 6;
  const int wm = wvi >> 1, wn = wvi & 1;
  const int m16 = lane & 15, quad = lane >> 4;

  f32x4 acc[4][4] = {};

  for (int k0 = 0; k0 < EK; k0 += 64) {
#pragma unroll
    for (int r = 0; r < 4; ++r) {
      async16(&As[tid * 8 + r * 2048], ga + (size_t)r * 32 * EK + k0);
      async16(&Bs[tid * 8 + r * 2048], gb + (size_t)r * 32 * EK + k0);
    }
    __syncthreads();
#pragma unroll
    for (int ks = 0; ks < 2; ++ks) {
      const int ko = ks * 32 + quad * 8;
      bf16x8 af[4], bfr[4];
#pragma unroll
      for (int i = 0; i < 4; ++i)
        af[i] = *(const bf16x8*)&As[(wm * 64 + i * 16 + m16) * 64 + ko];
#pragma unroll
      for (int j = 0; j < 4; ++j)
        bfr[j] = *(const bf16x8*)&Bs[(wn * 64 + j * 16 + m16) * 64 + ko];
#pragma unroll
      for (int i = 0; i < 4; ++i)
#pragma unroll
        for (int j = 0; j < 4; ++j) acc[i][j] = mfma16(af[i], bfr[j], acc[i][j]);
    }
    __syncthreads();
  }

#pragma unroll
  for (int i = 0; i < 4; ++i)
#pragma unroll
    for (int rr = 0; rr < 4; ++rr) {
      int row = by * 128 + wm * 64 + i * 16 + quad * 4 + rr;
      float* op = out + (size_t)row * DIM + bx * 128 + wn * 64 + m16;
#pragma unroll
      for (int j = 0; j < 4; ++j) op[j * 16] = acc[i][j][rr];
    }
}

// ---------------------------------------------------------------- launch
extern "C" void kernel_launch(void* const* d_in, const int* in_sizes, int n_in,
                              void* d_out, int out_size, void* d_ws, size_t ws_size,
                              hipStream_t stream) {
  const float* x  = (const float*)d_in[0];
  const float* Wr = (const float*)d_in[1];
  const float* br = (const float*)d_in[2];
  const float* A  = (const float*)d_in[3];
  const float* B  = (const float*)d_in[4];
  float* out = (float*)d_out;

  char* w = (char*)d_ws;
  u16* xb = (u16*)w;      w += (size_t)N_TOK * DIM * 2;        // 67.1 MB
  u16* G  = (u16*)w;      w += (size_t)N_TOK * EK * 2;         // 16.8 MB
  u16* Ab = (u16*)w;      w += (size_t)NEXP * RANK * DIM * 2;  //  8.4 MB
  u16* Bt = (u16*)w;      w += (size_t)DIM * EK * 2;           //  8.4 MB
  float* gw = (float*)w;  w += (size_t)N_TOK * 2 * 4;          // 64 KB
  int* lists = (int*)w;   w += (size_t)NEXP * N_TOK * 4;       // 256 KB
  int* cnt = (int*)w;     w += 256;

  hipMemsetAsync(cnt, 0, NEXP * sizeof(int), stream);
  hipMemsetAsync(G, 0, (size_t)N_TOK * EK * 2, stream);  // unselected blocks = 0

  cvtA_kernel<<<dim3(4096), dim3(256), 0, stream>>>(A, Ab);
  cvtB_kernel<<<dim3(4096), dim3(256), 0, stream>>>(B, Bt);
  router_kernel<<<dim3(1024), dim3(256), 0, stream>>>(x, Wr, br, xb, gw, lists, cnt);
  gemm1_kernel<<<dim3(128, NEXP), dim3(256), 0, stream>>>(xb, Ab, lists, cnt, gw, G);
  gemm2_kernel<<<dim3(32, 64), dim3(256), 0, stream>>>(G, Bt, out);
}

// Round 3
// 505.560 us; speedup vs baseline: 1.2059x; 1.2059x over previous
//
#include <hip/hip_runtime.h>

// Problem constants
#define N_TOK 8192
#define DIM   4096
#define NEXP  8
#define RANK  128
#define EK    (NEXP * RANK)   // 1024 = flattened (expert, rank) K dim for GEMM2
#define SCAL  0.25f           // LORA_ALPHA / R = 32/128

typedef unsigned short u16;
typedef __bf16 bf16x8 __attribute__((ext_vector_type(8)));
typedef float  f32x4  __attribute__((ext_vector_type(4)));

typedef const __attribute__((address_space(1))) void* as1_cvp;
typedef __attribute__((address_space(3))) void*       as3_vp;

__device__ __forceinline__ void async16(void* lds, const void* g) {
  // 16B-per-lane direct global->LDS (global_load_lds_dwordx4). LDS dest must be
  // wave-uniform base + lane*16 — all call sites arrange lds = base + tid*16B.
  __builtin_amdgcn_global_load_lds((as1_cvp)g, (as3_vp)lds, 16, 0, 0);
}

__device__ __forceinline__ u16 f2bf(float f) {  // RNE float->bf16 bits
  unsigned int u = __builtin_bit_cast(unsigned int, f);
  u += 0x7fffu + ((u >> 16) & 1u);
  return (u16)(u >> 16);
}

__device__ __forceinline__ f32x4 mfma16(bf16x8 a, bf16x8 b, f32x4 c) {
  return __builtin_amdgcn_mfma_f32_16x16x32_bf16(a, b, c, 0, 0, 0);
}

// ---------------------------------------------------------------- converts
__global__ __launch_bounds__(256) void cvtA_kernel(const float* __restrict__ A,
                                                   u16* __restrict__ Ab) {
  size_t i = (size_t)blockIdx.x * 256 + threadIdx.x;  // float4 index, same layout
  float4 v = ((const float4*)A)[i];
  ushort4 o;
  o.x = f2bf(v.x); o.y = f2bf(v.y); o.z = f2bf(v.z); o.w = f2bf(v.w);
  ((ushort4*)Ab)[i] = o;
}

// B[e][o][r] fp32 -> Bt[o][e*128+r] bf16 (BT layout for GEMM2, k-contiguous rows)
__global__ __launch_bounds__(256) void cvtB_kernel(const float* __restrict__ B,
                                                   u16* __restrict__ Bt) {
  size_t i = (size_t)blockIdx.x * 256 + threadIdx.x;  // enumerates (e, o, r/4)
  int r4 = (int)(i & 31);
  int o_ = (int)((i >> 5) & 4095);
  int e  = (int)(i >> 17);
  float4 v = ((const float4*)B)[i];
  ushort4 u;
  u.x = f2bf(v.x); u.y = f2bf(v.y); u.z = f2bf(v.z); u.w = f2bf(v.w);
  ((ushort4*)Bt)[(size_t)o_ * 256 + e * 32 + r4] = u;
}

// ---------------------------------------------------------------- router
// fp32 router (bf16 would flip near-tie expert picks), fused x->bf16 convert.
// R2 post-mortem: 16384 value-returning device atomics to ONE cache line
// serialized the whole kernel (16384 x ~30cyc = 204us = measured 203us, with
// VALU 5.7% / HBM 8% / LDS idle). R3: router writes only gw + packed sel[n];
// list building moves to a ballot-aggregated kernel (128 global atomics total).
__device__ __forceinline__ void router_finalize(
    int n, const float* l_in, const float* __restrict__ br,
    float* __restrict__ gw, int* __restrict__ sel) {
  float l[NEXP];
#pragma unroll
  for (int e = 0; e < NEXP; ++e) l[e] = l_in[e] + br[e];
  int i0 = 0;
#pragma unroll
  for (int e = 1; e < NEXP; ++e) if (l[e] > l[i0]) i0 = e;
  int i1 = (i0 == 0) ? 1 : 0;
#pragma unroll
  for (int e = 0; e < NEXP; ++e) if (e != i0 && l[e] > l[i1]) i1 = e;
  // renormalized top-2 gate: w0 = exp(l0)/(exp(l0)+exp(l1)); l1<=l0 so no ovf
  float w0 = 1.f / (1.f + expf(l[i1] - l[i0]));
  gw[n * 2 + 0] = w0 * SCAL;
  gw[n * 2 + 1] = (1.f - w0) * SCAL;
  sel[n] = i0 | (i1 << 4);
}

__global__ __launch_bounds__(256) void router_kernel(
    const float* __restrict__ x, const float* __restrict__ Wr,
    const float* __restrict__ br, u16* __restrict__ xb,
    float* __restrict__ gw, int* __restrict__ sel) {
  const int tid = threadIdx.x;
  const int wv = tid >> 6, lane = tid & 63;
  const int n0 = (blockIdx.x * 4 + wv) * 2;  // this wave's 2 tokens
  const float4* x4 = (const float4*)x;
  const float4* w4 = (const float4*)Wr;

  const float4* xr0 = x4 + (size_t)n0 * 1024;
  const float4* xr1 = x4 + (size_t)(n0 + 1) * 1024;
  ushort4* xo0 = (ushort4*)(xb + (size_t)n0 * DIM);
  ushort4* xo1 = (ushort4*)(xb + (size_t)(n0 + 1) * DIM);

  float s0[NEXP] = {}, s1[NEXP] = {};
#pragma unroll 4
  for (int it = 0; it < 16; ++it) {
    const int col = it * 64 + lane;  // float4 column index; lanes coalesced
    float4 xv0 = xr0[col];
    float4 xv1 = xr1[col];
    ushort4 o0, o1;
    o0.x = f2bf(xv0.x); o0.y = f2bf(xv0.y); o0.z = f2bf(xv0.z); o0.w = f2bf(xv0.w);
    o1.x = f2bf(xv1.x); o1.y = f2bf(xv1.y); o1.z = f2bf(xv1.z); o1.w = f2bf(xv1.w);
    xo0[col] = o0;
    xo1[col] = o1;
#pragma unroll
    for (int e = 0; e < NEXP; ++e) {
      float4 wv4 = w4[(size_t)e * 1024 + col];  // L2-resident (128 KB total)
      s0[e] += xv0.x * wv4.x + xv0.y * wv4.y + xv0.z * wv4.z + xv0.w * wv4.w;
      s1[e] += xv1.x * wv4.x + xv1.y * wv4.y + xv1.z * wv4.z + xv1.w * wv4.w;
    }
  }
  // one butterfly per wave (96 DS ops for 8192 loaded floats)
#pragma unroll
  for (int m = 1; m < 64; m <<= 1)
#pragma unroll
    for (int e = 0; e < NEXP; ++e) {
      s0[e] += __shfl_xor(s0[e], m, 64);
      s1[e] += __shfl_xor(s1[e], m, 64);
    }
  if (lane == 0)      router_finalize(n0,     s0, br, gw, sel);
  else if (lane == 1) router_finalize(n0 + 1, s1, br, gw, sel);
}

// ---------------------------------------------------------------- listbuild
// Ballot-aggregated expert-list compaction. 16 blocks x 512 thr, 1 token/thr.
// Wave ballots -> 8 LDS atomics/wave -> 8 global atomics/block (128 total,
// vs 16384 per-lane same-line atomics that cost 203us in R2). List order
// within an expert is nondeterministic; gemm1 is order-agnostic.
__global__ __launch_bounds__(512) void listbuild_kernel(
    const int* __restrict__ sel, int* __restrict__ lists,
    int* __restrict__ cnt) {
  __shared__ int blkCnt[NEXP];
  __shared__ int gBase[NEXP];
  __shared__ int waveOff[8][NEXP];
  const int tid = threadIdx.x;
  const int wv = tid >> 6, lane = tid & 63;
  const int n = blockIdx.x * 512 + tid;
  if (tid < NEXP) blkCnt[tid] = 0;
  __syncthreads();
  const int s = sel[n];
  const int i0 = s & 15, i1 = (s >> 4) & 15;
#pragma unroll
  for (int e = 0; e < NEXP; ++e) {
    unsigned long long m0 = __ballot(i0 == e);
    unsigned long long m1 = __ballot(i1 == e);
    if (lane == 0)
      waveOff[wv][e] = atomicAdd(&blkCnt[e], __popcll(m0) + __popcll(m1));
  }
  __syncthreads();
  if (tid < NEXP) gBase[tid] = atomicAdd(&cnt[tid], blkCnt[tid]);
  __syncthreads();
  const unsigned long long lt = (1ull << lane) - 1;
#pragma unroll
  for (int e = 0; e < NEXP; ++e) {
    unsigned long long m0 = __ballot(i0 == e);
    unsigned long long m1 = __ballot(i1 == e);
    int base = gBase[e] + waveOff[wv][e];
    if (i0 == e) lists[e * N_TOK + base + (int)__popcll(m0 & lt)] = n * 2;
    if (i1 == e)
      lists[e * N_TOK + base + (int)__popcll(m0) + (int)__popcll(m1 & lt)] =
          n * 2 + 1;
  }
}

// ---------------------------------------------------------------- GEMM1
// Per expert: h[entry, r] = xb[token] . Ab[e][r], scaled by gate*SCAL -> G bf16.
// Tile: 64 entries x 128 (full R) x BK=64, 256 threads (4 waves, each 32x64).
__global__ __launch_bounds__(256) void gemm1_kernel(
    const u16* __restrict__ xb, const u16* __restrict__ Ab,
    const int* __restrict__ lists, const int* __restrict__ cnt,
    const float* __restrict__ gw, u16* __restrict__ G) {
  const int e = blockIdx.y;
  const int mt = blockIdx.x;
  const int c = cnt[e];
  if (mt * 64 >= c) return;

  __shared__ alignas(16) u16 As[64 * 64];
  __shared__ alignas(16) u16 Bs[128 * 64];
  __shared__ int   tokS[64];
  __shared__ float wS[64];

  const int tid = threadIdx.x;
  if (tid < 64) {
    int idx = mt * 64 + tid;
    int ci = idx < c ? idx : (c - 1);
    int entry = lists[e * N_TOK + ci];
    tokS[tid] = entry >> 1;
    wS[tid] = (idx < c) ? gw[entry] : 0.0f;
  }
  __syncthreads();

  const int lr = tid >> 3;  // 0..31 staging row
  const int cg = tid & 7;   // 16B column group
  const u16* ga0 = xb + (size_t)tokS[lr] * DIM + cg * 8;
  const u16* ga1 = xb + (size_t)tokS[lr + 32] * DIM + cg * 8;
  const u16* gb  = Ab + (size_t)e * (RANK * DIM) + (size_t)lr * DIM + cg * 8;

  const int lane = tid & 63, wvi = tid >> 6;
  const int wm = wvi >> 1, wn = wvi & 1;
  const int m16 = lane & 15, quad = lane >> 4;

  f32x4 acc[2][4] = {};

  for (int k0 = 0; k0 < DIM; k0 += 64) {
    async16(&As[tid * 8], ga0 + k0);
    async16(&As[tid * 8 + 2048], ga1 + k0);
#pragma unroll
    for (int r = 0; r < 4; ++r)
      async16(&Bs[tid * 8 + r * 2048], gb + (size_t)r * 32 * DIM + k0);
    __syncthreads();
#pragma unroll
    for (int ks = 0; ks < 2; ++ks) {
      const int ko = ks * 32 + quad * 8;
      bf16x8 af[2], bfr[4];
#pragma unroll
      for (int i = 0; i < 2; ++i)
        af[i] = *(const bf16x8*)&As[(wm * 32 + i * 16 + m16) * 64 + ko];
#pragma unroll
      for (int j = 0; j < 4; ++j)
        bfr[j] = *(const bf16x8*)&Bs[(wn * 64 + j * 16 + m16) * 64 + ko];
#pragma unroll
      for (int i = 0; i < 2; ++i)
#pragma unroll
        for (int j = 0; j < 4; ++j) acc[i][j] = mfma16(af[i], bfr[j], acc[i][j]);
    }
    __syncthreads();
  }

#pragma unroll
  for (int i = 0; i < 2; ++i)
#pragma unroll
    for (int rr = 0; rr < 4; ++rr) {
      int row = wm * 32 + i * 16 + quad * 4 + rr;  // C/D: row=quad*4+reg
      if (mt * 64 + row < c) {
        int tk = tokS[row];
        float wgt = wS[row];
        u16* gp = G + (size_t)tk * EK + e * RANK + wn * 64 + m16;  // col=lane&15
#pragma unroll
        for (int j = 0; j < 4; ++j) gp[j * 16] = f2bf(acc[i][j][rr] * wgt);
      }
    }
}

// ---------------------------------------------------------------- GEMM2
// Dense: out[8192,4096] = G[8192,1024] @ Bt[4096,1024]^T. m97-style 128x128x64.
__global__ __launch_bounds__(256) void gemm2_kernel(
    const u16* __restrict__ G, const u16* __restrict__ Bt,
    float* __restrict__ out) {
  const int bx = blockIdx.x;  // n tile 0..31
  const int by = blockIdx.y;  // m tile 0..63
  __shared__ alignas(16) u16 As[128 * 64];
  __shared__ alignas(16) u16 Bs[128 * 64];

  const int tid = threadIdx.x;
  const int lr = tid >> 3, cg = tid & 7;
  const u16* ga = G  + (size_t)(by * 128 + lr) * EK + cg * 8;
  const u16* gb = Bt + (size_t)(bx * 128 + lr) * EK + cg * 8;

  const int lane = tid & 63, wvi = tid >> 6;
  const int wm = wvi >> 1, wn = wvi & 1;
  const int m16 = lane & 15, quad = lane >> 4;

  f32x4 acc[4][4] = {};

  for (int k0 = 0; k0 < EK; k0 += 64) {
#pragma unroll
    for (int r = 0; r < 4; ++r) {
      async16(&As[tid * 8 + r * 2048], ga + (size_t)r * 32 * EK + k0);
      async16(&Bs[tid * 8 + r * 2048], gb + (size_t)r * 32 * EK + k0);
    }
    __syncthreads();
#pragma unroll
    for (int ks = 0; ks < 2; ++ks) {
      const int ko = ks * 32 + quad * 8;
      bf16x8 af[4], bfr[4];
#pragma unroll
      for (int i = 0; i < 4; ++i)
        af[i] = *(const bf16x8*)&As[(wm * 64 + i * 16 + m16) * 64 + ko];
#pragma unroll
      for (int j = 0; j < 4; ++j)
        bfr[j] = *(const bf16x8*)&Bs[(wn * 64 + j * 16 + m16) * 64 + ko];
#pragma unroll
      for (int i = 0; i < 4; ++i)
#pragma unroll
        for (int j = 0; j < 4; ++j) acc[i][j] = mfma16(af[i], bfr[j], acc[i][j]);
    }
    __syncthreads();
  }

#pragma unroll
  for (int i = 0; i < 4; ++i)
#pragma unroll
    for (int rr = 0; rr < 4; ++rr) {
      int row = by * 128 + wm * 64 + i * 16 + quad * 4 + rr;
      float* op = out + (size_t)row * DIM + bx * 128 + wn * 64 + m16;
#pragma unroll
      for (int j = 0; j < 4; ++j) op[j * 16] = acc[i][j][rr];
    }
}

// ---------------------------------------------------------------- launch
extern "C" void kernel_launch(void* const* d_in, const int* in_sizes, int n_in,
                              void* d_out, int out_size, void* d_ws, size_t ws_size,
                              hipStream_t stream) {
  const float* x  = (const float*)d_in[0];
  const float* Wr = (const float*)d_in[1];
  const float* br = (const float*)d_in[2];
  const float* A  = (const float*)d_in[3];
  const float* B  = (const float*)d_in[4];
  float* out = (float*)d_out;

  char* w = (char*)d_ws;
  u16* xb = (u16*)w;      w += (size_t)N_TOK * DIM * 2;        // 67.1 MB
  u16* G  = (u16*)w;      w += (size_t)N_TOK * EK * 2;         // 16.8 MB
  u16* Ab = (u16*)w;      w += (size_t)NEXP * RANK * DIM * 2;  //  8.4 MB
  u16* Bt = (u16*)w;      w += (size_t)DIM * EK * 2;           //  8.4 MB
  float* gw = (float*)w;  w += (size_t)N_TOK * 2 * 4;          // 64 KB
  int* lists = (int*)w;   w += (size_t)NEXP * N_TOK * 4;       // 256 KB
  int* sel = (int*)w;     w += (size_t)N_TOK * 4;              // 32 KB
  int* cnt = (int*)w;     w += 256;

  hipMemsetAsync(cnt, 0, NEXP * sizeof(int), stream);
  hipMemsetAsync(G, 0, (size_t)N_TOK * EK * 2, stream);  // unselected blocks = 0

  cvtA_kernel<<<dim3(4096), dim3(256), 0, stream>>>(A, Ab);
  cvtB_kernel<<<dim3(4096), dim3(256), 0, stream>>>(B, Bt);
  router_kernel<<<dim3(1024), dim3(256), 0, stream>>>(x, Wr, br, xb, gw, sel);
  listbuild_kernel<<<dim3(16), dim3(512), 0, stream>>>(sel, lists, cnt);
  gemm1_kernel<<<dim3(128, NEXP), dim3(256), 0, stream>>>(xb, Ab, lists, cnt, gw, G);
  gemm2_kernel<<<dim3(32, 64), dim3(256), 0, stream>>>(G, Bt, out);
}